// Round 1
// 210.874 us; speedup vs baseline: 1.0184x; 1.0184x over previous
//
#include <hip/hip_runtime.h>
#include <hip/hip_bf16.h>
#include <cstdint>
#include <cstddef>

// Problem constants
#define SEQ   2048
#define HID   2048
#define NH    32
#define NKVH  8
#define HD    64
#define KVDIM (NKVH * HD)   // 512

typedef __bf16 bf16_t;
typedef __bf16 bf16x8 __attribute__((ext_vector_type(8)));
typedef float  f32x4  __attribute__((ext_vector_type(4)));

// log2(10000)/32  (RoPE: theta^(-d/32) = exp2(-d*L))
#define ROPE_L 0.4152410118609203f

// exp path: raw v_exp_f32 (2^x) if the builtin exists — then Q carries
// log2(e)/sqrt(HD); otherwise __expf with plain 1/sqrt(HD).
#if __has_builtin(__builtin_amdgcn_exp2f)
#define QSCALE 0.18033688011112043f
#define EXPFN(x) __builtin_amdgcn_exp2f(x)
#else
#define QSCALE 0.125f
#define EXPFN(x) __expf(x)
#endif

__device__ __forceinline__ bf16x8 load8(const float* p) {
    const float4 lo = *(const float4*)p;
    const float4 hi = *(const float4*)(p + 4);
    bf16x8 r;
    r[0] = (bf16_t)lo.x; r[1] = (bf16_t)lo.y; r[2] = (bf16_t)lo.z; r[3] = (bf16_t)lo.w;
    r[4] = (bf16_t)hi.x; r[5] = (bf16_t)hi.y; r[6] = (bf16_t)hi.z; r[7] = (bf16_t)hi.w;
    return r;
}

// async global->LDS, 16B per lane; LDS dest = wave-uniform base + lane*16
__device__ __forceinline__ void load_lds16(const bf16_t* g, bf16_t* l) {
    __builtin_amdgcn_global_load_lds((const __attribute__((address_space(1))) void*)g,
                                     (__attribute__((address_space(3))) void*)l,
                                     16, 0, 0);
}

// ---------------------------------------------------------------------------
// One-shot fp32 -> bf16 conversion of all GEMM operands (X, Wq, Wk, Wv, Wo).
// ---------------------------------------------------------------------------
#define NX  (SEQ * HID)          // 4M
#define NWQ (NH * HD * HID)      // 4M
#define NWK (KVDIM * HID)        // 1M
#define NWV (KVDIM * HID)        // 1M
#define NWO (HID * NH * HD)      // 4M
#define NTOT (NX + NWQ + NWK + NWV + NWO)   // 14M

__global__ __launch_bounds__(256) void cvt_all(const float* __restrict__ X,
                                               const float* __restrict__ Wq,
                                               const float* __restrict__ Wk,
                                               const float* __restrict__ Wv,
                                               const float* __restrict__ Wo,
                                               bf16_t* __restrict__ Xb,
                                               bf16_t* __restrict__ Wqb,
                                               bf16_t* __restrict__ Wkb,
                                               bf16_t* __restrict__ Wvb,
                                               bf16_t* __restrict__ Wob)
{
    size_t i = ((size_t)blockIdx.x * 256 + threadIdx.x) * 8;
    if (i >= NTOT) return;
    const size_t E0 = NX, E1 = E0 + NWQ, E2 = E1 + NWK, E3 = E2 + NWV;
    const float* s; bf16_t* d; size_t off;
    if (i < E0)      { s = X;  d = Xb;  off = i; }
    else if (i < E1) { s = Wq; d = Wqb; off = i - E0; }
    else if (i < E2) { s = Wk; d = Wkb; off = i - E1; }
    else if (i < E3) { s = Wv; d = Wvb; off = i - E2; }
    else             { s = Wo; d = Wob; off = i - E3; }
    *(bf16x8*)(d + off) = load8(s + off);
}

// ---------------------------------------------------------------------------
// Fused QKV projection + RoPE, 128x64 tiles (768 blocks = 3/CU).
// 4 waves stacked on M; each wave 32m x 64n = 2x4 mfma_f32_16x16x32_bf16.
// BK=64 per barrier pair (two 32-col half-buffers; rows stay 64B so the
// fragment-read bank pattern is unchanged) -> half the vmcnt(0)+barrier
// drains of the BK=32 version.  Q pre-scaled by QSCALE; V transposed.
// ---------------------------------------------------------------------------
__global__ __launch_bounds__(256) void qkv_gemm(const bf16_t* __restrict__ Xb,
                                                const bf16_t* __restrict__ Wqb,
                                                const bf16_t* __restrict__ Wkb,
                                                const bf16_t* __restrict__ Wvb,
                                                bf16_t* __restrict__ Qb,
                                                bf16_t* __restrict__ Kb,
                                                bf16_t* __restrict__ Vt)
{
    __shared__ alignas(16) bf16_t sa0[128 * 32], sa1[128 * 32];   // k 0-31 / 32-63
    __shared__ alignas(16) bf16_t sb0[64 * 32],  sb1[64 * 32];
    const int t = threadIdx.x;
    const int lane = t & 63;
    const int w  = t >> 6;
    const int n16 = lane & 15;
    const int q4  = lane >> 4;
    f32x4 acc[2][4] = {};

    const int m0 = blockIdx.x * 128;
    const int n0 = blockIdx.y * 64;

    const bf16_t* B;
    int mode, nc;
    if (n0 < NH * HD)              { B = Wqb + (size_t)n0 * HID;                     mode = 0; nc = n0; }
    else if (n0 < NH * HD + KVDIM) { B = Wkb + (size_t)(n0 - NH * HD) * HID;         mode = 1; nc = n0 - NH * HD; }
    else                           { B = Wvb + (size_t)(n0 - NH * HD - KVDIM) * HID; mode = 2; nc = n0 - NH * HD - KVDIM; }

    const int lrow = lane >> 2;          // 0..15
    const int lcol = (lane & 3) * 8;
    const bf16_t* ag = Xb + (size_t)(m0 + w * 16 + lrow) * HID + lcol;
    const bf16_t* bg = B  + (size_t)(w * 16 + lrow) * HID + lcol;
    bf16_t* la0  = &sa0[(w * 16) * 32];
    bf16_t* la1  = &sa1[(w * 16) * 32];
    bf16_t* la0b = &sa0[(64 + w * 16) * 32];
    bf16_t* la1b = &sa1[(64 + w * 16) * 32];
    bf16_t* lb0  = &sb0[(w * 16) * 32];
    bf16_t* lb1  = &sb1[(w * 16) * 32];

    for (int k0 = 0; k0 < HID; k0 += 64) {
        load_lds16(ag + k0,                        la0);
        load_lds16(ag + k0 + 32,                   la1);
        load_lds16(ag + (size_t)64 * HID + k0,      la0b);
        load_lds16(ag + (size_t)64 * HID + k0 + 32, la1b);
        load_lds16(bg + k0,      lb0);
        load_lds16(bg + k0 + 32, lb1);
        __syncthreads();
#pragma unroll
        for (int kk = 0; kk < 2; ++kk) {
            const bf16_t* sa = kk ? sa1 : sa0;
            const bf16_t* sb = kk ? sb1 : sb0;
            bf16x8 bfrag[4];
#pragma unroll
            for (int j = 0; j < 4; ++j)
                bfrag[j] = *(const bf16x8*)&sb[(j * 16 + n16) * 32 + q4 * 8];
#pragma unroll
            for (int i = 0; i < 2; ++i) {
                bf16x8 af = *(const bf16x8*)&sa[(w * 32 + i * 16 + n16) * 32 + q4 * 8];
#pragma unroll
                for (int j = 0; j < 4; ++j)
                    acc[i][j] = __builtin_amdgcn_mfma_f32_16x16x32_bf16(af, bfrag[j], acc[i][j], 0, 0, 0);
            }
        }
        __syncthreads();
    }

    if (mode < 2) {
        // ---- RoPE in registers: d = jt*16+n16 (jt<2), partner at jt+2 ----
#pragma unroll
        for (int jt = 0; jt < 2; ++jt) {
            float dd = (float)(jt * 16 + n16);
            float inv = exp2f(-dd * ROPE_L);
#pragma unroll
            for (int i = 0; i < 2; ++i) {
#pragma unroll
                for (int r = 0; r < 4; ++r) {
                    int pos = m0 + w * 32 + i * 16 + q4 * 4 + r;
                    float ang = (float)pos * inv;
                    float sn, cs;
                    sincosf(ang, &sn, &cs);
                    float x1 = acc[i][jt][r], x2 = acc[i][jt + 2][r];
                    acc[i][jt][r]     = x1 * cs - x2 * sn;
                    acc[i][jt + 2][r] = x2 * cs + x1 * sn;
                }
            }
        }
        const float osc = (mode == 0) ? QSCALE : 1.0f;
        bf16_t* dst = (mode == 0) ? Qb : Kb;
        const int ld = (mode == 0) ? NH * HD : KVDIM;
#pragma unroll
        for (int i = 0; i < 2; ++i)
#pragma unroll
            for (int j = 0; j < 4; ++j) {
                int row = m0 + w * 32 + i * 16 + q4 * 4;
                int col = nc + j * 16 + n16;
#pragma unroll
                for (int r = 0; r < 4; ++r)
                    dst[(size_t)(row + r) * ld + col] = (bf16_t)(acc[i][j][r] * osc);
            }
    } else {
        // ---- V: store transposed, 4 consecutive rows per lane contiguous ----
#pragma unroll
        for (int i = 0; i < 2; ++i)
#pragma unroll
            for (int j = 0; j < 4; ++j) {
                int row = m0 + w * 32 + i * 16 + q4 * 4;
                int col = nc + j * 16 + n16;
#pragma unroll
                for (int r = 0; r < 4; ++r)
                    Vt[(size_t)col * SEQ + row + r] = (bf16_t)acc[i][j][r];
            }
    }
}

// ---------------------------------------------------------------------------
// O projection, 128x64 tiles (512 blocks = 2/CU), BK=64 half-buffers.
// ---------------------------------------------------------------------------
__global__ __launch_bounds__(256) void o_gemm(const bf16_t* __restrict__ A,
                                              const bf16_t* __restrict__ Bw,
                                              float* __restrict__ C)
{
    __shared__ alignas(16) bf16_t sa0[128 * 32], sa1[128 * 32];
    __shared__ alignas(16) bf16_t sb0[64 * 32],  sb1[64 * 32];
    const int t = threadIdx.x;
    const int lane = t & 63;
    const int w  = t >> 6;
    const int n16 = lane & 15;
    const int q4  = lane >> 4;
    f32x4 acc[2][4] = {};

    const int m0 = blockIdx.x * 128;
    const int n0 = blockIdx.y * 64;

    const int lrow = lane >> 2;
    const int lcol = (lane & 3) * 8;
    const bf16_t* ag = A  + (size_t)(m0 + w * 16 + lrow) * HID + lcol;
    const bf16_t* bg = Bw + (size_t)(n0 + w * 16 + lrow) * HID + lcol;
    bf16_t* la0  = &sa0[(w * 16) * 32];
    bf16_t* la1  = &sa1[(w * 16) * 32];
    bf16_t* la0b = &sa0[(64 + w * 16) * 32];
    bf16_t* la1b = &sa1[(64 + w * 16) * 32];
    bf16_t* lb0  = &sb0[(w * 16) * 32];
    bf16_t* lb1  = &sb1[(w * 16) * 32];

    for (int k0 = 0; k0 < HID; k0 += 64) {
        load_lds16(ag + k0,                        la0);
        load_lds16(ag + k0 + 32,                   la1);
        load_lds16(ag + (size_t)64 * HID + k0,      la0b);
        load_lds16(ag + (size_t)64 * HID + k0 + 32, la1b);
        load_lds16(bg + k0,      lb0);
        load_lds16(bg + k0 + 32, lb1);
        __syncthreads();
#pragma unroll
        for (int kk = 0; kk < 2; ++kk) {
            const bf16_t* sa = kk ? sa1 : sa0;
            const bf16_t* sb = kk ? sb1 : sb0;
            bf16x8 bfrag[4];
#pragma unroll
            for (int j = 0; j < 4; ++j)
                bfrag[j] = *(const bf16x8*)&sb[(j * 16 + n16) * 32 + q4 * 8];
#pragma unroll
            for (int i = 0; i < 2; ++i) {
                bf16x8 af = *(const bf16x8*)&sa[(w * 32 + i * 16 + n16) * 32 + q4 * 8];
#pragma unroll
                for (int j = 0; j < 4; ++j)
                    acc[i][j] = __builtin_amdgcn_mfma_f32_16x16x32_bf16(af, bfrag[j], acc[i][j], 0, 0, 0);
            }
        }
        __syncthreads();
    }

#pragma unroll
    for (int i = 0; i < 2; ++i)
#pragma unroll
        for (int j = 0; j < 4; ++j) {
            int row = m0 + w * 32 + i * 16 + q4 * 4;
            int col = n0 + j * 16 + n16;
#pragma unroll
            for (int r = 0; r < 4; ++r)
                C[(size_t)(row + r) * HID + col] = acc[i][j][r];
        }
}

// ---------------------------------------------------------------------------
// MFMA causal flash attention v2: Bq=128 per block, 4 waves x 32 q-rows.
// Cycle model of the old 16-row/wave structure: ~400 LDS-pipe cy per wave
// per 64x64 kv-tile vs 90 MFMA cy -> LDS-instruction bound (matches the
// measured 44-49us / MfmaUtil 16%).  32 rows/wave reuses each K/V fragment
// across two row-fragments: 20 ds_read_b128 + 32 swizzled b16 stores for
// 36 MFMA (~2.5x better FLOP per LDS-cycle).
// P staging: row stride 40 elems (80B -> q4 parity reaches bank bit 4) plus
// col ^ ((row>>2&2)<<3); each ds_write_b16 now hits all 32 banks (2 lanes
// per bank in the SAME dword), vs 16 banks / 4-way before (the measured
// 7.03M conflict-cycles == ~6.5 extra cy x 1.08M b16 stores).
// Heavy/light pairing: blocks [0,256) take qt 15..8, [256,512) take 0..7,
// so block b and b+256 (same XCD by round-robin) sum to ~constant work.
// ---------------------------------------------------------------------------
__global__ __launch_bounds__(256, 3) void attn_mfma(const bf16_t* __restrict__ Qm,
                                                    const bf16_t* __restrict__ Km,
                                                    const bf16_t* __restrict__ Vt,
                                                    bf16_t* __restrict__ Om)
{
    const int bid = blockIdx.x;
    const int h   = bid & (NH - 1);
    const int qt  = (bid < (SEQ / 128) * NH / 2)
                      ? (SEQ / 128 - 1 - (bid >> 5))
                      : ((bid - (SEQ / 128) * NH / 2) >> 5);
    const int q0  = qt * 128;
    const int kvh = h >> 2;            // H/KVH = 4
    const int t    = threadIdx.x;
    const int w    = t >> 6;
    const int lane = t & 63;
    const int n16  = lane & 15;
    const int q4   = lane >> 4;

    __shared__ alignas(16) bf16_t kA[128 * 32];
    __shared__ alignas(16) bf16_t kB[128 * 32];
    __shared__ alignas(16) bf16_t vc0[64 * 32], vc1[64 * 32];
    __shared__ alignas(16) bf16_t vc2[64 * 32], vc3[64 * 32];
    __shared__ alignas(16) bf16_t ps[4][2][32 * 40];   // [wave][k-half][swizzled 32x40]

    // Q fragments in registers: rows q0 + w*32 + i*16 + n16
    bf16x8 qf[2][2];
#pragma unroll
    for (int i = 0; i < 2; ++i) {
        const bf16_t* qp = Qm + (size_t)(q0 + w * 32 + i * 16 + n16) * HID + h * HD;
        qf[i][0] = *(const bf16x8*)(qp + q4 * 8);
        qf[i][1] = *(const bf16x8*)(qp + 32 + q4 * 8);
    }

    f32x4 acc[2][4] = {};
    f32x4 acc_l[2] = {};                 // row-sums of P via ones-MFMA
    const bf16_t one = (bf16_t)1.0f;
    const bf16x8 ones8 = {one, one, one, one, one, one, one, one};

    const int srow = lane >> 2;
    const int scol = (lane & 3) * 8;
    const bf16_t* kg = Km + (size_t)kvh * HD + scol;
    const bf16_t* vg = Vt + (size_t)(kvh * HD) * SEQ;

    const int my_last = 2 * qt + (w >> 1);     // last 64-kv tile this wave needs
    const int wkey   = (q4 & 2) << 3;          // P-store swizzle ((row>>2)&2)<<3
    const int rdkey  = ((n16 >> 2) & 2) << 3;  // same bit for row = n16 / 16+n16

    for (int kb = 0; kb <= qt; ++kb) {
        const int k0 = kb * 128;
        {
            const int r0 = w * 16 + srow;
            const bf16_t* kp0 = kg + (size_t)(k0 + r0) * KVDIM;
            const bf16_t* kp1 = kg + (size_t)(k0 + 64 + r0) * KVDIM;
            load_lds16(kp0,      &kA[(w * 16) * 32]);
            load_lds16(kp0 + 32, &kB[(w * 16) * 32]);
            load_lds16(kp1,      &kA[(64 + w * 16) * 32]);
            load_lds16(kp1 + 32, &kB[(64 + w * 16) * 32]);
            const bf16_t* vp = vg + (size_t)r0 * SEQ + k0 + scol;
            load_lds16(vp,      &vc0[(w * 16) * 32]);
            load_lds16(vp + 32, &vc1[(w * 16) * 32]);
            load_lds16(vp + 64, &vc2[(w * 16) * 32]);
            load_lds16(vp + 96, &vc3[(w * 16) * 32]);
        }
        __syncthreads();

        for (int hh = 0; hh < 2; ++hh) {
            const int gh = 2 * kb + hh;
            if (gh > my_last) break;                       // wave-uniform
            const bf16_t* kAh = &kA[hh * 64 * 32];
            const bf16_t* kBh = &kB[hh * 64 * 32];
            const bf16_t* vAh = hh ? vc2 : vc0;
            const bf16_t* vBh = hh ? vc3 : vc1;

            // ---- S' = Q' K^T (log2-domain scores); K frags reused over i ----
            f32x4 st[2][4];
#pragma unroll
            for (int jt = 0; jt < 4; ++jt) {
                bf16x8 kf0 = *(const bf16x8*)&kAh[(jt * 16 + n16) * 32 + q4 * 8];
                bf16x8 kf1 = *(const bf16x8*)&kBh[(jt * 16 + n16) * 32 + q4 * 8];
#pragma unroll
                for (int i = 0; i < 2; ++i) {
                    f32x4 s = {};
                    s = __builtin_amdgcn_mfma_f32_16x16x32_bf16(qf[i][0], kf0, s, 0, 0, 0);
                    s = __builtin_amdgcn_mfma_f32_16x16x32_bf16(qf[i][1], kf1, s, 0, 0, 0);
                    st[i][jt] = s;
                }
            }

            // ---- causal mask: only this wave's diagonal tile ----
            if (gh == my_last) {
#pragma unroll
                for (int i = 0; i < 2; ++i) {
                    int rowb = q0 + w * 32 + i * 16 + q4 * 4;
#pragma unroll
                    for (int jt = 0; jt < 4; ++jt) {
                        int colg = gh * 64 + jt * 16 + n16;
#pragma unroll
                        for (int r = 0; r < 4; ++r)
                            if (colg > rowb + r) st[i][jt][r] = -1e30f;
                    }
                }
            }

            // ---- exp (raw v_exp_f32 path) ----
#pragma unroll
            for (int i = 0; i < 2; ++i)
#pragma unroll
                for (int jt = 0; jt < 4; ++jt)
#pragma unroll
                    for (int r = 0; r < 4; ++r)
                        st[i][jt][r] = EXPFN(st[i][jt][r]);

            // ---- P: C-layout regs -> per-wave LDS, bank-swizzled ----
#pragma unroll
            for (int i = 0; i < 2; ++i)
#pragma unroll
                for (int jt = 0; jt < 4; ++jt) {
                    bf16_t* ph = ps[w][jt >> 1];
                    int rowb = i * 16 + q4 * 4;
                    int csw  = ((jt & 1) * 16 + n16) ^ wkey;
#pragma unroll
                    for (int r = 0; r < 4; ++r)
                        ph[(rowb + r) * 40 + csw] = (bf16_t)st[i][jt][r];
                }

            bf16x8 pf[2][2];
#pragma unroll
            for (int i = 0; i < 2; ++i) {
                int ra = (i * 16 + n16) * 40 + ((q4 * 8) ^ rdkey);
                pf[i][0] = *(const bf16x8*)&ps[w][0][ra];
                pf[i][1] = *(const bf16x8*)&ps[w][1][ra];
            }

            // ---- l += row-sum(P) via ones-MFMA ----
#pragma unroll
            for (int i = 0; i < 2; ++i) {
                acc_l[i] = __builtin_amdgcn_mfma_f32_16x16x32_bf16(pf[i][0], ones8, acc_l[i], 0, 0, 0);
                acc_l[i] = __builtin_amdgcn_mfma_f32_16x16x32_bf16(pf[i][1], ones8, acc_l[i], 0, 0, 0);
            }

            // ---- O += P V (V frags reused over i) ----
#pragma unroll
            for (int jd = 0; jd < 4; ++jd) {
                bf16x8 vf0 = *(const bf16x8*)&vAh[(jd * 16 + n16) * 32 + q4 * 8];
                bf16x8 vf1 = *(const bf16x8*)&vBh[(jd * 16 + n16) * 32 + q4 * 8];
#pragma unroll
                for (int i = 0; i < 2; ++i) {
                    acc[i][jd] = __builtin_amdgcn_mfma_f32_16x16x32_bf16(pf[i][0], vf0, acc[i][jd], 0, 0, 0);
                    acc[i][jd] = __builtin_amdgcn_mfma_f32_16x16x32_bf16(pf[i][1], vf1, acc[i][jd], 0, 0, 0);
                }
            }
        }
        __syncthreads();
    }

    // ---- normalize + store ----
#pragma unroll
    for (int i = 0; i < 2; ++i) {
        float linv[4];
#pragma unroll
        for (int r = 0; r < 4; ++r) linv[r] = 1.0f / acc_l[i][r];
#pragma unroll
        for (int jd = 0; jd < 4; ++jd)
#pragma unroll
            for (int r = 0; r < 4; ++r) {
                int rowg = q0 + w * 32 + i * 16 + q4 * 4 + r;
                Om[(size_t)rowg * HID + h * HD + jd * 16 + n16] = (bf16_t)(acc[i][jd][r] * linv[r]);
            }
    }
}

// ---------------------------------------------------------------------------
extern "C" void kernel_launch(void* const* d_in, const int* in_sizes, int n_in,
                              void* d_out, int out_size, void* d_ws, size_t ws_size,
                              hipStream_t stream)
{
    const float* X  = (const float*)d_in[0];
    const float* Wq = (const float*)d_in[1];
    const float* Wk = (const float*)d_in[2];
    const float* Wv = (const float*)d_in[3];
    const float* Wo = (const float*)d_in[4];
    float* out = (float*)d_out;

    bf16_t* Xb  = (bf16_t*)d_ws;                      // [SEQ][HID]     8 MB
    bf16_t* Wqb = Xb  + (size_t)NX;                   // [2048][2048]   8 MB
    bf16_t* Wkb = Wqb + (size_t)NWQ;                  // [512][2048]    2 MB
    bf16_t* Wvb = Wkb + (size_t)NWK;                  // [512][2048]    2 MB
    bf16_t* Wob = Wvb + (size_t)NWV;                  // [2048][2048]   8 MB
    bf16_t* Qb  = Wob + (size_t)NWO;                  // [SEQ][NH*HD]   8 MB (pre-scaled QSCALE)
    bf16_t* Kb  = Qb  + (size_t)SEQ * (NH * HD);      // [SEQ][KVDIM]   2 MB
    bf16_t* Vt  = Kb  + (size_t)SEQ * KVDIM;          // [KVDIM][SEQ]   2 MB
    bf16_t* Ob  = Vt  + (size_t)SEQ * KVDIM;          // [SEQ][NH*HD]   8 MB

    dim3 blk(256);

    // one-shot fp32 -> bf16 conversion of all operands
    cvt_all<<<dim3((NTOT / 8 + 255) / 256), blk, 0, stream>>>(X, Wq, Wk, Wv, Wo, Xb, Wqb, Wkb, Wvb, Wob);

    // fused QKV projection + RoPE (128x64 tiles, BK=64)
    qkv_gemm<<<dim3(SEQ / 128, (NH * HD + 2 * KVDIM) / 64), blk, 0, stream>>>(Xb, Wqb, Wkb, Wvb, Qb, Kb, Vt);

    // causal GQA attention (Bq=128, 512 blocks, heavy/light paired)
    attn_mfma<<<dim3((SEQ / 128) * NH), blk, 0, stream>>>(Qb, Kb, Vt, Ob);

    // output projection -> d_out (128x64 tiles, BK=64)
    o_gemm<<<dim3(SEQ / 128, HID / 64), blk, 0, stream>>>(Ob, Wob, out);
}

// Round 2
// 201.580 us; speedup vs baseline: 1.0653x; 1.0461x over previous
//
#include <hip/hip_runtime.h>
#include <hip/hip_bf16.h>
#include <cstdint>
#include <cstddef>

// Problem constants
#define SEQ   2048
#define HID   2048
#define NH    32
#define NKVH  8
#define HD    64
#define KVDIM (NKVH * HD)   // 512

typedef __bf16 bf16_t;
typedef __bf16 bf16x8 __attribute__((ext_vector_type(8)));
typedef float  f32x4  __attribute__((ext_vector_type(4)));

// log2(10000)/32  (RoPE: theta^(-d/32) = exp2(-d*L))
#define ROPE_L 0.4152410118609203f

// exp path: raw v_exp_f32 (2^x) if the builtin exists — then Q carries
// log2(e)/sqrt(HD); otherwise __expf with plain 1/sqrt(HD).
#if __has_builtin(__builtin_amdgcn_exp2f)
#define QSCALE 0.18033688011112043f
#define EXPFN(x) __builtin_amdgcn_exp2f(x)
#else
#define QSCALE 0.125f
#define EXPFN(x) __expf(x)
#endif

__device__ __forceinline__ bf16x8 load8(const float* p) {
    const float4 lo = *(const float4*)p;
    const float4 hi = *(const float4*)(p + 4);
    bf16x8 r;
    r[0] = (bf16_t)lo.x; r[1] = (bf16_t)lo.y; r[2] = (bf16_t)lo.z; r[3] = (bf16_t)lo.w;
    r[4] = (bf16_t)hi.x; r[5] = (bf16_t)hi.y; r[6] = (bf16_t)hi.z; r[7] = (bf16_t)hi.w;
    return r;
}

// async global->LDS, 16B per lane; LDS dest = wave-uniform base + lane*16
__device__ __forceinline__ void load_lds16(const bf16_t* g, bf16_t* l) {
    __builtin_amdgcn_global_load_lds((const __attribute__((address_space(1))) void*)g,
                                     (__attribute__((address_space(3))) void*)l,
                                     16, 0, 0);
}

// ---------------------------------------------------------------------------
// One-shot fp32 -> bf16 conversion of all GEMM operands (X, Wq, Wk, Wv, Wo).
// ---------------------------------------------------------------------------
#define NX  (SEQ * HID)          // 4M
#define NWQ (NH * HD * HID)      // 4M
#define NWK (KVDIM * HID)        // 1M
#define NWV (KVDIM * HID)        // 1M
#define NWO (HID * NH * HD)      // 4M
#define NTOT (NX + NWQ + NWK + NWV + NWO)   // 14M

__global__ __launch_bounds__(256) void cvt_all(const float* __restrict__ X,
                                               const float* __restrict__ Wq,
                                               const float* __restrict__ Wk,
                                               const float* __restrict__ Wv,
                                               const float* __restrict__ Wo,
                                               bf16_t* __restrict__ Xb,
                                               bf16_t* __restrict__ Wqb,
                                               bf16_t* __restrict__ Wkb,
                                               bf16_t* __restrict__ Wvb,
                                               bf16_t* __restrict__ Wob)
{
    size_t i = ((size_t)blockIdx.x * 256 + threadIdx.x) * 8;
    if (i >= NTOT) return;
    const size_t E0 = NX, E1 = E0 + NWQ, E2 = E1 + NWK, E3 = E2 + NWV;
    const float* s; bf16_t* d; size_t off;
    if (i < E0)      { s = X;  d = Xb;  off = i; }
    else if (i < E1) { s = Wq; d = Wqb; off = i - E0; }
    else if (i < E2) { s = Wk; d = Wkb; off = i - E1; }
    else if (i < E3) { s = Wv; d = Wvb; off = i - E2; }
    else             { s = Wo; d = Wob; off = i - E3; }
    *(bf16x8*)(d + off) = load8(s + off);
}

// ---------------------------------------------------------------------------
// Fused QKV projection + RoPE, 128x64 tiles (768 blocks = 3/CU).
// T3-min 2-phase pipeline: double-buffered LDS staging (48 KB), STAGE(k+64)
// issued BEFORE compute(k) so the __syncthreads vmcnt(0) drain only pays the
// residual of loads that already overlapped a full 16-MFMA compute phase.
// Loop unrolled x2 -> all buffer indices static.
// ---------------------------------------------------------------------------
__global__ __launch_bounds__(256) void qkv_gemm(const bf16_t* __restrict__ Xb,
                                                const bf16_t* __restrict__ Wqb,
                                                const bf16_t* __restrict__ Wkb,
                                                const bf16_t* __restrict__ Wvb,
                                                bf16_t* __restrict__ Qb,
                                                bf16_t* __restrict__ Kb,
                                                bf16_t* __restrict__ Vt)
{
    __shared__ alignas(16) bf16_t sA00[128 * 32], sA01[128 * 32];   // buf0: k, k+32
    __shared__ alignas(16) bf16_t sA10[128 * 32], sA11[128 * 32];   // buf1
    __shared__ alignas(16) bf16_t sB00[64 * 32],  sB01[64 * 32];
    __shared__ alignas(16) bf16_t sB10[64 * 32],  sB11[64 * 32];
    const int t = threadIdx.x;
    const int lane = t & 63;
    const int w  = t >> 6;
    const int n16 = lane & 15;
    const int q4  = lane >> 4;
    f32x4 acc[2][4] = {};

    const int m0 = blockIdx.x * 128;
    const int n0 = blockIdx.y * 64;

    const bf16_t* B;
    int mode, nc;
    if (n0 < NH * HD)              { B = Wqb + (size_t)n0 * HID;                     mode = 0; nc = n0; }
    else if (n0 < NH * HD + KVDIM) { B = Wkb + (size_t)(n0 - NH * HD) * HID;         mode = 1; nc = n0 - NH * HD; }
    else                           { B = Wvb + (size_t)(n0 - NH * HD - KVDIM) * HID; mode = 2; nc = n0 - NH * HD - KVDIM; }

    const int lrow = lane >> 2;          // 0..15
    const int lcol = (lane & 3) * 8;
    const bf16_t* ag = Xb + (size_t)(m0 + w * 16 + lrow) * HID + lcol;
    const bf16_t* bg = B  + (size_t)(w * 16 + lrow) * HID + lcol;

    auto stage = [&](bf16_t* a0, bf16_t* a1, bf16_t* b0, bf16_t* b1, int k0) {
        load_lds16(ag + k0,                         a0 + (w * 16) * 32);
        load_lds16(ag + k0 + 32,                    a1 + (w * 16) * 32);
        load_lds16(ag + (size_t)64 * HID + k0,      a0 + (64 + w * 16) * 32);
        load_lds16(ag + (size_t)64 * HID + k0 + 32, a1 + (64 + w * 16) * 32);
        load_lds16(bg + k0,      b0 + (w * 16) * 32);
        load_lds16(bg + k0 + 32, b1 + (w * 16) * 32);
    };
    auto mma_step = [&](const bf16_t* sa, const bf16_t* sb) {
        bf16x8 bfrag[4];
#pragma unroll
        for (int j = 0; j < 4; ++j)
            bfrag[j] = *(const bf16x8*)&sb[(j * 16 + n16) * 32 + q4 * 8];
#pragma unroll
        for (int i = 0; i < 2; ++i) {
            bf16x8 af = *(const bf16x8*)&sa[(w * 32 + i * 16 + n16) * 32 + q4 * 8];
#pragma unroll
            for (int j = 0; j < 4; ++j)
                acc[i][j] = __builtin_amdgcn_mfma_f32_16x16x32_bf16(af, bfrag[j], acc[i][j], 0, 0, 0);
        }
    };

    stage(sA00, sA01, sB00, sB01, 0);
    __syncthreads();
    for (int k0 = 0; k0 < HID; k0 += 128) {
        if (k0 + 64 < HID) stage(sA10, sA11, sB10, sB11, k0 + 64);
        mma_step(sA00, sB00);
        mma_step(sA01, sB01);
        __syncthreads();
        if (k0 + 128 < HID) stage(sA00, sA01, sB00, sB01, k0 + 128);
        mma_step(sA10, sB10);
        mma_step(sA11, sB11);
        __syncthreads();
    }

    if (mode < 2) {
        // ---- RoPE in registers: d = jt*16+n16 (jt<2), partner at jt+2 ----
#pragma unroll
        for (int jt = 0; jt < 2; ++jt) {
            float dd = (float)(jt * 16 + n16);
            float inv = exp2f(-dd * ROPE_L);
#pragma unroll
            for (int i = 0; i < 2; ++i) {
#pragma unroll
                for (int r = 0; r < 4; ++r) {
                    int pos = m0 + w * 32 + i * 16 + q4 * 4 + r;
                    float ang = (float)pos * inv;
                    float sn, cs;
                    sincosf(ang, &sn, &cs);
                    float x1 = acc[i][jt][r], x2 = acc[i][jt + 2][r];
                    acc[i][jt][r]     = x1 * cs - x2 * sn;
                    acc[i][jt + 2][r] = x2 * cs + x1 * sn;
                }
            }
        }
        const float osc = (mode == 0) ? QSCALE : 1.0f;
        bf16_t* dst = (mode == 0) ? Qb : Kb;
        const int ld = (mode == 0) ? NH * HD : KVDIM;
#pragma unroll
        for (int i = 0; i < 2; ++i)
#pragma unroll
            for (int j = 0; j < 4; ++j) {
                int row = m0 + w * 32 + i * 16 + q4 * 4;
                int col = nc + j * 16 + n16;
#pragma unroll
                for (int r = 0; r < 4; ++r)
                    dst[(size_t)(row + r) * ld + col] = (bf16_t)(acc[i][j][r] * osc);
            }
    } else {
        // ---- V: store transposed, 4 consecutive rows per lane contiguous ----
#pragma unroll
        for (int i = 0; i < 2; ++i)
#pragma unroll
            for (int j = 0; j < 4; ++j) {
                int row = m0 + w * 32 + i * 16 + q4 * 4;
                int col = nc + j * 16 + n16;
#pragma unroll
                for (int r = 0; r < 4; ++r)
                    Vt[(size_t)col * SEQ + row + r] = (bf16_t)acc[i][j][r];
            }
    }
}

// ---------------------------------------------------------------------------
// O projection, 128x64 tiles (512 blocks = 2/CU), same 2-phase pipeline.
// ---------------------------------------------------------------------------
__global__ __launch_bounds__(256) void o_gemm(const bf16_t* __restrict__ A,
                                              const bf16_t* __restrict__ Bw,
                                              float* __restrict__ C)
{
    __shared__ alignas(16) bf16_t sA00[128 * 32], sA01[128 * 32];
    __shared__ alignas(16) bf16_t sA10[128 * 32], sA11[128 * 32];
    __shared__ alignas(16) bf16_t sB00[64 * 32],  sB01[64 * 32];
    __shared__ alignas(16) bf16_t sB10[64 * 32],  sB11[64 * 32];
    const int t = threadIdx.x;
    const int lane = t & 63;
    const int w  = t >> 6;
    const int n16 = lane & 15;
    const int q4  = lane >> 4;
    f32x4 acc[2][4] = {};

    const int m0 = blockIdx.x * 128;
    const int n0 = blockIdx.y * 64;

    const int lrow = lane >> 2;
    const int lcol = (lane & 3) * 8;
    const bf16_t* ag = A  + (size_t)(m0 + w * 16 + lrow) * HID + lcol;
    const bf16_t* bg = Bw + (size_t)(n0 + w * 16 + lrow) * HID + lcol;

    auto stage = [&](bf16_t* a0, bf16_t* a1, bf16_t* b0, bf16_t* b1, int k0) {
        load_lds16(ag + k0,                         a0 + (w * 16) * 32);
        load_lds16(ag + k0 + 32,                    a1 + (w * 16) * 32);
        load_lds16(ag + (size_t)64 * HID + k0,      a0 + (64 + w * 16) * 32);
        load_lds16(ag + (size_t)64 * HID + k0 + 32, a1 + (64 + w * 16) * 32);
        load_lds16(bg + k0,      b0 + (w * 16) * 32);
        load_lds16(bg + k0 + 32, b1 + (w * 16) * 32);
    };
    auto mma_step = [&](const bf16_t* sa, const bf16_t* sb) {
        bf16x8 bfrag[4];
#pragma unroll
        for (int j = 0; j < 4; ++j)
            bfrag[j] = *(const bf16x8*)&sb[(j * 16 + n16) * 32 + q4 * 8];
#pragma unroll
        for (int i = 0; i < 2; ++i) {
            bf16x8 af = *(const bf16x8*)&sa[(w * 32 + i * 16 + n16) * 32 + q4 * 8];
#pragma unroll
            for (int j = 0; j < 4; ++j)
                acc[i][j] = __builtin_amdgcn_mfma_f32_16x16x32_bf16(af, bfrag[j], acc[i][j], 0, 0, 0);
        }
    };

    stage(sA00, sA01, sB00, sB01, 0);
    __syncthreads();
    for (int k0 = 0; k0 < HID; k0 += 128) {
        if (k0 + 64 < HID) stage(sA10, sA11, sB10, sB11, k0 + 64);
        mma_step(sA00, sB00);
        mma_step(sA01, sB01);
        __syncthreads();
        if (k0 + 128 < HID) stage(sA00, sA01, sB00, sB01, k0 + 128);
        mma_step(sA10, sB10);
        mma_step(sA11, sB11);
        __syncthreads();
    }

#pragma unroll
    for (int i = 0; i < 2; ++i)
#pragma unroll
        for (int j = 0; j < 4; ++j) {
            int row = m0 + w * 32 + i * 16 + q4 * 4;
            int col = n0 + j * 16 + n16;
#pragma unroll
            for (int r = 0; r < 4; ++r)
                C[(size_t)(row + r) * HID + col] = acc[i][j][r];
        }
}

// ---------------------------------------------------------------------------
// MFMA causal flash attention v3: Bq=128, 4 waves x 32 q-rows, with a
// T3-min 2-phase K/V staging pipeline at 64-kv granularity.
// Per 64-kv tile: K (64x64, 8KB) + V (64x64, 8KB) double-buffered = 32KB,
// + per-wave swizzled P staging 20KB = 52KB LDS (unchanged occupancy).
// STAGE(gh+1) is issued BEFORE compute(gh); the __syncthreads vmcnt(0)
// drain then only pays load residual (loads overlap ~800cy of compute).
// gh-count = 2qt+2 is always even -> unroll x2, static buffer indices.
// s_setprio(1) wraps the MFMA clusters (T5, +4-7% on attn-like schedules).
// ---------------------------------------------------------------------------
__global__ __launch_bounds__(256, 3) void attn_mfma(const bf16_t* __restrict__ Qm,
                                                    const bf16_t* __restrict__ Km,
                                                    const bf16_t* __restrict__ Vt,
                                                    bf16_t* __restrict__ Om)
{
    const int bid = blockIdx.x;
    const int h   = bid & (NH - 1);
    const int qt  = (bid < (SEQ / 128) * NH / 2)
                      ? (SEQ / 128 - 1 - (bid >> 5))
                      : ((bid - (SEQ / 128) * NH / 2) >> 5);
    const int q0  = qt * 128;
    const int kvh = h >> 2;            // H/KVH = 4
    const int t    = threadIdx.x;
    const int w    = t >> 6;
    const int lane = t & 63;
    const int n16  = lane & 15;
    const int q4   = lane >> 4;

    __shared__ alignas(16) bf16_t k0A[64 * 32], k0B[64 * 32];   // buf0: K cols 0-31 / 32-63
    __shared__ alignas(16) bf16_t k1A[64 * 32], k1B[64 * 32];   // buf1
    __shared__ alignas(16) bf16_t v0A[64 * 32], v0B[64 * 32];   // buf0: V k-cols 0-31 / 32-63
    __shared__ alignas(16) bf16_t v1A[64 * 32], v1B[64 * 32];   // buf1
    __shared__ alignas(16) bf16_t ps[4][2][32 * 40];   // [wave][k-half][swizzled 32x40]

    // Q fragments in registers: rows q0 + w*32 + i*16 + n16
    bf16x8 qf[2][2];
#pragma unroll
    for (int i = 0; i < 2; ++i) {
        const bf16_t* qp = Qm + (size_t)(q0 + w * 32 + i * 16 + n16) * HID + h * HD;
        qf[i][0] = *(const bf16x8*)(qp + q4 * 8);
        qf[i][1] = *(const bf16x8*)(qp + 32 + q4 * 8);
    }

    f32x4 acc[2][4] = {};
    f32x4 acc_l[2] = {};                 // row-sums of P via ones-MFMA
    const bf16_t one = (bf16_t)1.0f;
    const bf16x8 ones8 = {one, one, one, one, one, one, one, one};

    const int srow = lane >> 2;
    const int scol = (lane & 3) * 8;
    const int r0   = w * 16 + srow;
    const bf16_t* kg = Km + (size_t)kvh * HD + scol;
    const bf16_t* vg = Vt + (size_t)(kvh * HD) * SEQ;

    const int ghmax  = 2 * qt + 1;             // last 64-kv tile staged (odd)
    const int my_last = 2 * qt + (w >> 1);     // last 64-kv tile this wave computes
    const int wkey   = (q4 & 2) << 3;          // P-store swizzle ((row>>2)&2)<<3
    const int rdkey  = ((n16 >> 2) & 2) << 3;  // same bit for read rows

    auto stage = [&](int gh, bf16_t* kA_, bf16_t* kB_, bf16_t* vA_, bf16_t* vB_) {
        const int k0 = gh * 64;
        const bf16_t* kp = kg + (size_t)(k0 + r0) * KVDIM;
        load_lds16(kp,      kA_ + (w * 16) * 32);
        load_lds16(kp + 32, kB_ + (w * 16) * 32);
        const bf16_t* vp = vg + (size_t)r0 * SEQ + k0 + scol;
        load_lds16(vp,      vA_ + (w * 16) * 32);
        load_lds16(vp + 32, vB_ + (w * 16) * 32);
    };

    auto compute = [&](int gh, const bf16_t* kAh, const bf16_t* kBh,
                       const bf16_t* vAh, const bf16_t* vBh) {
        // ---- S' = Q' K^T (log2-domain scores); K frags reused over i ----
        f32x4 st[2][4];
        __builtin_amdgcn_s_setprio(1);
#pragma unroll
        for (int jt = 0; jt < 4; ++jt) {
            bf16x8 kf0 = *(const bf16x8*)&kAh[(jt * 16 + n16) * 32 + q4 * 8];
            bf16x8 kf1 = *(const bf16x8*)&kBh[(jt * 16 + n16) * 32 + q4 * 8];
#pragma unroll
            for (int i = 0; i < 2; ++i) {
                f32x4 s = {};
                s = __builtin_amdgcn_mfma_f32_16x16x32_bf16(qf[i][0], kf0, s, 0, 0, 0);
                s = __builtin_amdgcn_mfma_f32_16x16x32_bf16(qf[i][1], kf1, s, 0, 0, 0);
                st[i][jt] = s;
            }
        }
        __builtin_amdgcn_s_setprio(0);

        // ---- causal mask: only this wave's diagonal tile ----
        if (gh == my_last) {
#pragma unroll
            for (int i = 0; i < 2; ++i) {
                int rowb = q0 + w * 32 + i * 16 + q4 * 4;
#pragma unroll
                for (int jt = 0; jt < 4; ++jt) {
                    int colg = gh * 64 + jt * 16 + n16;
#pragma unroll
                    for (int r = 0; r < 4; ++r)
                        if (colg > rowb + r) st[i][jt][r] = -1e30f;
                }
            }
        }

        // ---- exp (raw v_exp_f32 path) ----
#pragma unroll
        for (int i = 0; i < 2; ++i)
#pragma unroll
            for (int jt = 0; jt < 4; ++jt)
#pragma unroll
                for (int r = 0; r < 4; ++r)
                    st[i][jt][r] = EXPFN(st[i][jt][r]);

        // ---- P: C-layout regs -> per-wave LDS, bank-swizzled ----
#pragma unroll
        for (int i = 0; i < 2; ++i)
#pragma unroll
            for (int jt = 0; jt < 4; ++jt) {
                bf16_t* ph = ps[w][jt >> 1];
                int rowb = i * 16 + q4 * 4;
                int csw  = ((jt & 1) * 16 + n16) ^ wkey;
#pragma unroll
                for (int r = 0; r < 4; ++r)
                    ph[(rowb + r) * 40 + csw] = (bf16_t)st[i][jt][r];
            }

        bf16x8 pf[2][2];
#pragma unroll
        for (int i = 0; i < 2; ++i) {
            int ra = (i * 16 + n16) * 40 + ((q4 * 8) ^ rdkey);
            pf[i][0] = *(const bf16x8*)&ps[w][0][ra];
            pf[i][1] = *(const bf16x8*)&ps[w][1][ra];
        }

        __builtin_amdgcn_s_setprio(1);
        // ---- l += row-sum(P) via ones-MFMA ----
#pragma unroll
        for (int i = 0; i < 2; ++i) {
            acc_l[i] = __builtin_amdgcn_mfma_f32_16x16x32_bf16(pf[i][0], ones8, acc_l[i], 0, 0, 0);
            acc_l[i] = __builtin_amdgcn_mfma_f32_16x16x32_bf16(pf[i][1], ones8, acc_l[i], 0, 0, 0);
        }
        // ---- O += P V (V frags reused over i) ----
#pragma unroll
        for (int jd = 0; jd < 4; ++jd) {
            bf16x8 vf0 = *(const bf16x8*)&vAh[(jd * 16 + n16) * 32 + q4 * 8];
            bf16x8 vf1 = *(const bf16x8*)&vBh[(jd * 16 + n16) * 32 + q4 * 8];
#pragma unroll
            for (int i = 0; i < 2; ++i) {
                acc[i][jd] = __builtin_amdgcn_mfma_f32_16x16x32_bf16(pf[i][0], vf0, acc[i][jd], 0, 0, 0);
                acc[i][jd] = __builtin_amdgcn_mfma_f32_16x16x32_bf16(pf[i][1], vf1, acc[i][jd], 0, 0, 0);
            }
        }
        __builtin_amdgcn_s_setprio(0);
    };

    // ---- 2-phase pipelined main loop (gh-count = 2qt+2, always even) ----
    stage(0, k0A, k0B, v0A, v0B);
    __syncthreads();
    for (int gh = 0; gh <= ghmax; gh += 2) {
        if (gh < ghmax) stage(gh + 1, k1A, k1B, v1A, v1B);
        if (gh <= my_last) compute(gh, k0A, k0B, v0A, v0B);
        __syncthreads();
        if (gh + 1 < ghmax) stage(gh + 2, k0A, k0B, v0A, v0B);
        if (gh + 1 <= my_last) compute(gh + 1, k1A, k1B, v1A, v1B);
        __syncthreads();
    }

    // ---- normalize + store ----
#pragma unroll
    for (int i = 0; i < 2; ++i) {
        float linv[4];
#pragma unroll
        for (int r = 0; r < 4; ++r) linv[r] = 1.0f / acc_l[i][r];
#pragma unroll
        for (int jd = 0; jd < 4; ++jd)
#pragma unroll
            for (int r = 0; r < 4; ++r) {
                int rowg = q0 + w * 32 + i * 16 + q4 * 4 + r;
                Om[(size_t)rowg * HID + h * HD + jd * 16 + n16] = (bf16_t)(acc[i][jd][r] * linv[r]);
            }
    }
}

// ---------------------------------------------------------------------------
extern "C" void kernel_launch(void* const* d_in, const int* in_sizes, int n_in,
                              void* d_out, int out_size, void* d_ws, size_t ws_size,
                              hipStream_t stream)
{
    const float* X  = (const float*)d_in[0];
    const float* Wq = (const float*)d_in[1];
    const float* Wk = (const float*)d_in[2];
    const float* Wv = (const float*)d_in[3];
    const float* Wo = (const float*)d_in[4];
    float* out = (float*)d_out;

    bf16_t* Xb  = (bf16_t*)d_ws;                      // [SEQ][HID]     8 MB
    bf16_t* Wqb = Xb  + (size_t)NX;                   // [2048][2048]   8 MB
    bf16_t* Wkb = Wqb + (size_t)NWQ;                  // [512][2048]    2 MB
    bf16_t* Wvb = Wkb + (size_t)NWK;                  // [512][2048]    2 MB
    bf16_t* Wob = Wvb + (size_t)NWV;                  // [2048][2048]   8 MB
    bf16_t* Qb  = Wob + (size_t)NWO;                  // [SEQ][NH*HD]   8 MB (pre-scaled QSCALE)
    bf16_t* Kb  = Qb  + (size_t)SEQ * (NH * HD);      // [SEQ][KVDIM]   2 MB
    bf16_t* Vt  = Kb  + (size_t)SEQ * KVDIM;          // [KVDIM][SEQ]   2 MB
    bf16_t* Ob  = Vt  + (size_t)SEQ * KVDIM;          // [SEQ][NH*HD]   8 MB

    dim3 blk(256);

    // one-shot fp32 -> bf16 conversion of all operands
    cvt_all<<<dim3((NTOT / 8 + 255) / 256), blk, 0, stream>>>(X, Wq, Wk, Wv, Wo, Xb, Wqb, Wkb, Wvb, Wob);

    // fused QKV projection + RoPE (128x64 tiles, BK=64, 2-phase pipeline)
    qkv_gemm<<<dim3(SEQ / 128, (NH * HD + 2 * KVDIM) / 64), blk, 0, stream>>>(Xb, Wqb, Wkb, Wvb, Qb, Kb, Vt);

    // causal GQA attention (Bq=128, 512 blocks, 2-phase K/V pipeline)
    attn_mfma<<<dim3((SEQ / 128) * NH), blk, 0, stream>>>(Qb, Kb, Vt, Ob);

    // output projection -> d_out (128x64 tiles, BK=64, 2-phase pipeline)
    o_gemm<<<dim3(SEQ / 128, HID / 64), blk, 0, stream>>>(Ob, Wob, out);
}

// Round 5
// 195.827 us; speedup vs baseline: 1.0966x; 1.0294x over previous
//
#include <hip/hip_runtime.h>
#include <hip/hip_bf16.h>
#include <cstdint>
#include <cstddef>

// Problem constants
#define SEQ   2048
#define HID   2048
#define NH    32
#define NKVH  8
#define HD    64
#define KVDIM (NKVH * HD)   // 512

typedef __bf16 bf16_t;
typedef __bf16 bf16x8 __attribute__((ext_vector_type(8)));
typedef float  f32x4  __attribute__((ext_vector_type(4)));

// log2(10000)/32  (RoPE: theta^(-d/32) = exp2(-d*L))
#define ROPE_L 0.4152410118609203f

#if __has_builtin(__builtin_amdgcn_exp2f)
#define QSCALE 0.18033688011112043f
#define EXPFN(x) __builtin_amdgcn_exp2f(x)
#else
#define QSCALE 0.125f
#define EXPFN(x) __expf(x)
#endif

__device__ __forceinline__ bf16x8 load8(const float* p) {
    const float4 lo = *(const float4*)p;
    const float4 hi = *(const float4*)(p + 4);
    bf16x8 r;
    r[0] = (bf16_t)lo.x; r[1] = (bf16_t)lo.y; r[2] = (bf16_t)lo.z; r[3] = (bf16_t)lo.w;
    r[4] = (bf16_t)hi.x; r[5] = (bf16_t)hi.y; r[6] = (bf16_t)hi.z; r[7] = (bf16_t)hi.w;
    return r;
}

// async global->LDS, 16B per lane; LDS dest = wave-uniform base + lane*16
__device__ __forceinline__ void load_lds16(const bf16_t* g, bf16_t* l) {
    __builtin_amdgcn_global_load_lds((const __attribute__((address_space(1))) void*)g,
                                     (__attribute__((address_space(3))) void*)l,
                                     16, 0, 0);
}

// ---------------------------------------------------------------------------
// One-shot fp32 -> bf16 conversion of all GEMM operands.
// ---------------------------------------------------------------------------
#define NX  (SEQ * HID)          // 4M
#define NWQ (NH * HD * HID)      // 4M
#define NWK (KVDIM * HID)        // 1M
#define NWV (KVDIM * HID)        // 1M
#define NWO (HID * NH * HD)      // 4M
#define NTOT (NX + NWQ + NWK + NWV + NWO)   // 14M

__global__ __launch_bounds__(256) void cvt_all(const float* __restrict__ X,
                                               const float* __restrict__ Wq,
                                               const float* __restrict__ Wk,
                                               const float* __restrict__ Wv,
                                               const float* __restrict__ Wo,
                                               bf16_t* __restrict__ Xb,
                                               bf16_t* __restrict__ Wqb,
                                               bf16_t* __restrict__ Wkb,
                                               bf16_t* __restrict__ Wvb,
                                               bf16_t* __restrict__ Wob)
{
    size_t i = ((size_t)blockIdx.x * 256 + threadIdx.x) * 8;
    if (i >= NTOT) return;
    const size_t E0 = NX, E1 = E0 + NWQ, E2 = E1 + NWK, E3 = E2 + NWV;
    const float* s; bf16_t* d; size_t off;
    if (i < E0)      { s = X;  d = Xb;  off = i; }
    else if (i < E1) { s = Wq; d = Wqb; off = i - E0; }
    else if (i < E2) { s = Wk; d = Wkb; off = i - E1; }
    else if (i < E3) { s = Wv; d = Wvb; off = i - E2; }
    else             { s = Wo; d = Wob; off = i - E3; }
    *(bf16x8*)(d + off) = load8(s + off);
}

// ---------------------------------------------------------------------------
// Swizzled-tile convention (T2, both-sides, rule #21):
//   LDS tile = [rows][64] bf16, 128B rows.  Physical 16B slot s of row r
//   holds LOGICAL k-group (s ^ (r&7)).  Staging: linear LDS dest, per-lane
//   pre-swizzled global source: lane L covers row base+(L>>3), slot L&7,
//   so its global col-group is (L&7)^(L>>3)  (k-invariant).
//   Reads: logical group G of row r lives at slot G ^ (r&7); fragment rows
//   (..*16 + n16) have r&7 == n16&7.  Quarter-wave bank check: 16 lanes
//   (q4 fixed) hit 8 distinct 16B slots = 32 banks, 2 accesses/bank = min.
// ---------------------------------------------------------------------------

// ---------------------------------------------------------------------------
// Fused QKV projection + RoPE, 128x64 tiles (768 blocks = 3/CU), BK=64,
// 2-phase pipeline, swizzled 128B-row LDS tiles (conflict-free frag reads).
// ---------------------------------------------------------------------------
__global__ __launch_bounds__(256) void qkv_gemm(const bf16_t* __restrict__ Xb,
                                                const bf16_t* __restrict__ Wqb,
                                                const bf16_t* __restrict__ Wkb,
                                                const bf16_t* __restrict__ Wvb,
                                                bf16_t* __restrict__ Qb,
                                                bf16_t* __restrict__ Kb,
                                                bf16_t* __restrict__ Vt)
{
    __shared__ alignas(16) bf16_t sa0[128 * 64], sa1[128 * 64];   // 16KB each
    __shared__ alignas(16) bf16_t sb0[64 * 64],  sb1[64 * 64];    // 8KB each
    const int t = threadIdx.x;
    const int lane = t & 63;
    const int w  = t >> 6;
    const int n16 = lane & 15;
    const int q4  = lane >> 4;
    f32x4 acc[2][4] = {};

    const int m0 = blockIdx.x * 128;
    const int n0 = blockIdx.y * 64;

    const bf16_t* B;
    int mode, nc;
    if (n0 < NH * HD)              { B = Wqb + (size_t)n0 * HID;                     mode = 0; nc = n0; }
    else if (n0 < NH * HD + KVDIM) { B = Wkb + (size_t)(n0 - NH * HD) * HID;         mode = 1; nc = n0 - NH * HD; }
    else                           { B = Wvb + (size_t)(n0 - NH * HD - KVDIM) * HID; mode = 2; nc = n0 - NH * HD - KVDIM; }

    const int lrow8 = lane >> 3;                 // 0..7 (row within 8-row chunk)
    const int lgrp  = (lane & 7) ^ lrow8;        // pre-swizzled source col-group
    const bf16_t* ag = Xb + (size_t)(m0 + w * 8 + lrow8) * HID + lgrp * 8;
    const bf16_t* bg = B  + (size_t)(w * 8 + lrow8) * HID + lgrp * 8;

    auto stage = [&](bf16_t* da, bf16_t* db, int k0) {
#pragma unroll
        for (int s = 0; s < 4; ++s)     // A: 128 rows = 16 chunks, 4/wave
            load_lds16(ag + (size_t)(s * 32) * HID + k0, da + (w * 8 + s * 32) * 64);
#pragma unroll
        for (int s = 0; s < 2; ++s)     // B: 64 rows = 8 chunks, 2/wave
            load_lds16(bg + (size_t)(s * 32) * HID + k0, db + (w * 8 + s * 32) * 64);
    };
    auto mma_step = [&](const bf16_t* sa, const bf16_t* sb) {
#pragma unroll
        for (int kk = 0; kk < 2; ++kk) {
            const int xo = ((kk * 4 + q4) ^ (n16 & 7)) * 8;
            bf16x8 bfrag[4];
#pragma unroll
            for (int j = 0; j < 4; ++j)
                bfrag[j] = *(const bf16x8*)&sb[(j * 16 + n16) * 64 + xo];
#pragma unroll
            for (int i = 0; i < 2; ++i) {
                bf16x8 af = *(const bf16x8*)&sa[(w * 32 + i * 16 + n16) * 64 + xo];
#pragma unroll
                for (int j = 0; j < 4; ++j)
                    acc[i][j] = __builtin_amdgcn_mfma_f32_16x16x32_bf16(af, bfrag[j], acc[i][j], 0, 0, 0);
            }
        }
    };

    stage(sa0, sb0, 0);
    __syncthreads();
    for (int k0 = 0; k0 < HID; k0 += 128) {
        if (k0 + 64 < HID) stage(sa1, sb1, k0 + 64);
        mma_step(sa0, sb0);
        __syncthreads();
        if (k0 + 128 < HID) stage(sa0, sb0, k0 + 128);
        mma_step(sa1, sb1);
        __syncthreads();
    }

    if (mode < 2) {
        // ---- RoPE in registers: d = jt*16+n16 (jt<2), partner at jt+2 ----
#pragma unroll
        for (int jt = 0; jt < 2; ++jt) {
            float dd = (float)(jt * 16 + n16);
            float inv = exp2f(-dd * ROPE_L);
#pragma unroll
            for (int i = 0; i < 2; ++i) {
#pragma unroll
                for (int r = 0; r < 4; ++r) {
                    int pos = m0 + w * 32 + i * 16 + q4 * 4 + r;
                    float ang = (float)pos * inv;
                    float sn, cs;
                    sincosf(ang, &sn, &cs);
                    float x1 = acc[i][jt][r], x2 = acc[i][jt + 2][r];
                    acc[i][jt][r]     = x1 * cs - x2 * sn;
                    acc[i][jt + 2][r] = x2 * cs + x1 * sn;
                }
            }
        }
        const float osc = (mode == 0) ? QSCALE : 1.0f;
        bf16_t* dst = (mode == 0) ? Qb : Kb;
        const int ld = (mode == 0) ? NH * HD : KVDIM;
#pragma unroll
        for (int i = 0; i < 2; ++i)
#pragma unroll
            for (int j = 0; j < 4; ++j) {
                int row = m0 + w * 32 + i * 16 + q4 * 4;
                int col = nc + j * 16 + n16;
#pragma unroll
                for (int r = 0; r < 4; ++r)
                    dst[(size_t)(row + r) * ld + col] = (bf16_t)(acc[i][j][r] * osc);
            }
    } else {
        // ---- V: store transposed ----
#pragma unroll
        for (int i = 0; i < 2; ++i)
#pragma unroll
            for (int j = 0; j < 4; ++j) {
                int row = m0 + w * 32 + i * 16 + q4 * 4;
                int col = nc + j * 16 + n16;
#pragma unroll
                for (int r = 0; r < 4; ++r)
                    Vt[(size_t)col * SEQ + row + r] = (bf16_t)acc[i][j][r];
            }
    }
}

// ---------------------------------------------------------------------------
// O projection, 128x64 tiles (512 blocks), BK=64, 2-phase, swizzled tiles.
// ---------------------------------------------------------------------------
__global__ __launch_bounds__(256) void o_gemm(const bf16_t* __restrict__ A,
                                              const bf16_t* __restrict__ Bw,
                                              float* __restrict__ C)
{
    __shared__ alignas(16) bf16_t sa0[128 * 64], sa1[128 * 64];
    __shared__ alignas(16) bf16_t sb0[64 * 64],  sb1[64 * 64];
    const int t = threadIdx.x;
    const int lane = t & 63;
    const int w  = t >> 6;
    const int n16 = lane & 15;
    const int q4  = lane >> 4;
    f32x4 acc[2][4] = {};

    const int m0 = blockIdx.x * 128;
    const int n0 = blockIdx.y * 64;

    const int lrow8 = lane >> 3;
    const int lgrp  = (lane & 7) ^ lrow8;
    const bf16_t* ag = A  + (size_t)(m0 + w * 8 + lrow8) * HID + lgrp * 8;
    const bf16_t* bg = Bw + (size_t)(n0 + w * 8 + lrow8) * HID + lgrp * 8;

    auto stage = [&](bf16_t* da, bf16_t* db, int k0) {
#pragma unroll
        for (int s = 0; s < 4; ++s)
            load_lds16(ag + (size_t)(s * 32) * HID + k0, da + (w * 8 + s * 32) * 64);
#pragma unroll
        for (int s = 0; s < 2; ++s)
            load_lds16(bg + (size_t)(s * 32) * HID + k0, db + (w * 8 + s * 32) * 64);
    };
    auto mma_step = [&](const bf16_t* sa, const bf16_t* sb) {
#pragma unroll
        for (int kk = 0; kk < 2; ++kk) {
            const int xo = ((kk * 4 + q4) ^ (n16 & 7)) * 8;
            bf16x8 bfrag[4];
#pragma unroll
            for (int j = 0; j < 4; ++j)
                bfrag[j] = *(const bf16x8*)&sb[(j * 16 + n16) * 64 + xo];
#pragma unroll
            for (int i = 0; i < 2; ++i) {
                bf16x8 af = *(const bf16x8*)&sa[(w * 32 + i * 16 + n16) * 64 + xo];
#pragma unroll
                for (int j = 0; j < 4; ++j)
                    acc[i][j] = __builtin_amdgcn_mfma_f32_16x16x32_bf16(af, bfrag[j], acc[i][j], 0, 0, 0);
            }
        }
    };

    stage(sa0, sb0, 0);
    __syncthreads();
    for (int k0 = 0; k0 < HID; k0 += 128) {
        if (k0 + 64 < HID) stage(sa1, sb1, k0 + 64);
        mma_step(sa0, sb0);
        __syncthreads();
        if (k0 + 128 < HID) stage(sa0, sb0, k0 + 128);
        mma_step(sa1, sb1);
        __syncthreads();
    }

#pragma unroll
    for (int i = 0; i < 2; ++i)
#pragma unroll
        for (int j = 0; j < 4; ++j) {
            int row = m0 + w * 32 + i * 16 + q4 * 4;
            int col = n0 + j * 16 + n16;
#pragma unroll
            for (int r = 0; r < 4; ++r)
                C[(size_t)(row + r) * HID + col] = acc[i][j][r];
        }
}

// ---------------------------------------------------------------------------
// MFMA causal flash attention — byte-for-byte the R2 version that ran at
// 201.6us total (Bq=128, 4 waves x 32 q-rows, 2-phase 64-kv pipeline,
// 64x32 LDS tiles).  Reverted to isolate the R3 container failures.
// ---------------------------------------------------------------------------
__global__ __launch_bounds__(256, 3) void attn_mfma(const bf16_t* __restrict__ Qm,
                                                    const bf16_t* __restrict__ Km,
                                                    const bf16_t* __restrict__ Vt,
                                                    bf16_t* __restrict__ Om)
{
    const int bid = blockIdx.x;
    const int h   = bid & (NH - 1);
    const int qt  = (bid < (SEQ / 128) * NH / 2)
                      ? (SEQ / 128 - 1 - (bid >> 5))
                      : ((bid - (SEQ / 128) * NH / 2) >> 5);
    const int q0  = qt * 128;
    const int kvh = h >> 2;            // H/KVH = 4
    const int t    = threadIdx.x;
    const int w    = t >> 6;
    const int lane = t & 63;
    const int n16  = lane & 15;
    const int q4   = lane >> 4;

    __shared__ alignas(16) bf16_t k0A[64 * 32], k0B[64 * 32];   // buf0: K cols 0-31 / 32-63
    __shared__ alignas(16) bf16_t k1A[64 * 32], k1B[64 * 32];   // buf1
    __shared__ alignas(16) bf16_t v0A[64 * 32], v0B[64 * 32];   // buf0: V k-cols 0-31 / 32-63
    __shared__ alignas(16) bf16_t v1A[64 * 32], v1B[64 * 32];   // buf1
    __shared__ alignas(16) bf16_t ps[4][2][32 * 40];   // [wave][k-half][swizzled 32x40]

    // Q fragments in registers: rows q0 + w*32 + i*16 + n16
    bf16x8 qf[2][2];
#pragma unroll
    for (int i = 0; i < 2; ++i) {
        const bf16_t* qp = Qm + (size_t)(q0 + w * 32 + i * 16 + n16) * HID + h * HD;
        qf[i][0] = *(const bf16x8*)(qp + q4 * 8);
        qf[i][1] = *(const bf16x8*)(qp + 32 + q4 * 8);
    }

    f32x4 acc[2][4] = {};
    f32x4 acc_l[2] = {};                 // row-sums of P via ones-MFMA
    const bf16_t one = (bf16_t)1.0f;
    const bf16x8 ones8 = {one, one, one, one, one, one, one, one};

    const int srow = lane >> 2;
    const int scol = (lane & 3) * 8;
    const int r0   = w * 16 + srow;
    const bf16_t* kg = Km + (size_t)kvh * HD + scol;
    const bf16_t* vg = Vt + (size_t)(kvh * HD) * SEQ;

    const int ghmax  = 2 * qt + 1;             // last 64-kv tile staged (odd)
    const int my_last = 2 * qt + (w >> 1);     // last 64-kv tile this wave computes
    const int wkey   = (q4 & 2) << 3;          // P-store swizzle ((row>>2)&2)<<3
    const int rdkey  = ((n16 >> 2) & 2) << 3;  // same bit for read rows

    auto stage = [&](int gh, bf16_t* kA_, bf16_t* kB_, bf16_t* vA_, bf16_t* vB_) {
        const int k0 = gh * 64;
        const bf16_t* kp = kg + (size_t)(k0 + r0) * KVDIM;
        load_lds16(kp,      kA_ + (w * 16) * 32);
        load_lds16(kp + 32, kB_ + (w * 16) * 32);
        const bf16_t* vp = vg + (size_t)r0 * SEQ + k0 + scol;
        load_lds16(vp,      vA_ + (w * 16) * 32);
        load_lds16(vp + 32, vB_ + (w * 16) * 32);
    };

    auto compute = [&](int gh, const bf16_t* kAh, const bf16_t* kBh,
                       const bf16_t* vAh, const bf16_t* vBh) {
        // ---- S' = Q' K^T (log2-domain scores); K frags reused over i ----
        f32x4 st[2][4];
        __builtin_amdgcn_s_setprio(1);
#pragma unroll
        for (int jt = 0; jt < 4; ++jt) {
            bf16x8 kf0 = *(const bf16x8*)&kAh[(jt * 16 + n16) * 32 + q4 * 8];
            bf16x8 kf1 = *(const bf16x8*)&kBh[(jt * 16 + n16) * 32 + q4 * 8];
#pragma unroll
            for (int i = 0; i < 2; ++i) {
                f32x4 s = {};
                s = __builtin_amdgcn_mfma_f32_16x16x32_bf16(qf[i][0], kf0, s, 0, 0, 0);
                s = __builtin_amdgcn_mfma_f32_16x16x32_bf16(qf[i][1], kf1, s, 0, 0, 0);
                st[i][jt] = s;
            }
        }
        __builtin_amdgcn_s_setprio(0);

        // ---- causal mask: only this wave's diagonal tile ----
        if (gh == my_last) {
#pragma unroll
            for (int i = 0; i < 2; ++i) {
                int rowb = q0 + w * 32 + i * 16 + q4 * 4;
#pragma unroll
                for (int jt = 0; jt < 4; ++jt) {
                    int colg = gh * 64 + jt * 16 + n16;
#pragma unroll
                    for (int r = 0; r < 4; ++r)
                        if (colg > rowb + r) st[i][jt][r] = -1e30f;
                }
            }
        }

        // ---- exp (raw v_exp_f32 path) ----
#pragma unroll
        for (int i = 0; i < 2; ++i)
#pragma unroll
            for (int jt = 0; jt < 4; ++jt)
#pragma unroll
                for (int r = 0; r < 4; ++r)
                    st[i][jt][r] = EXPFN(st[i][jt][r]);

        // ---- P: C-layout regs -> per-wave LDS, bank-swizzled ----
#pragma unroll
        for (int i = 0; i < 2; ++i)
#pragma unroll
            for (int jt = 0; jt < 4; ++jt) {
                bf16_t* ph = ps[w][jt >> 1];
                int rowb = i * 16 + q4 * 4;
                int csw  = ((jt & 1) * 16 + n16) ^ wkey;
#pragma unroll
                for (int r = 0; r < 4; ++r)
                    ph[(rowb + r) * 40 + csw] = (bf16_t)st[i][jt][r];
            }

        bf16x8 pf[2][2];
#pragma unroll
        for (int i = 0; i < 2; ++i) {
            int ra = (i * 16 + n16) * 40 + ((q4 * 8) ^ rdkey);
            pf[i][0] = *(const bf16x8*)&ps[w][0][ra];
            pf[i][1] = *(const bf16x8*)&ps[w][1][ra];
        }

        __builtin_amdgcn_s_setprio(1);
        // ---- l += row-sum(P) via ones-MFMA ----
#pragma unroll
        for (int i = 0; i < 2; ++i) {
            acc_l[i] = __builtin_amdgcn_mfma_f32_16x16x32_bf16(pf[i][0], ones8, acc_l[i], 0, 0, 0);
            acc_l[i] = __builtin_amdgcn_mfma_f32_16x16x32_bf16(pf[i][1], ones8, acc_l[i], 0, 0, 0);
        }
        // ---- O += P V (V frags reused over i) ----
#pragma unroll
        for (int jd = 0; jd < 4; ++jd) {
            bf16x8 vf0 = *(const bf16x8*)&vAh[(jd * 16 + n16) * 32 + q4 * 8];
            bf16x8 vf1 = *(const bf16x8*)&vBh[(jd * 16 + n16) * 32 + q4 * 8];
#pragma unroll
            for (int i = 0; i < 2; ++i) {
                acc[i][jd] = __builtin_amdgcn_mfma_f32_16x16x32_bf16(pf[i][0], vf0, acc[i][jd], 0, 0, 0);
                acc[i][jd] = __builtin_amdgcn_mfma_f32_16x16x32_bf16(pf[i][1], vf1, acc[i][jd], 0, 0, 0);
            }
        }
        __builtin_amdgcn_s_setprio(0);
    };

    // ---- 2-phase pipelined main loop (gh-count = 2qt+2, always even) ----
    stage(0, k0A, k0B, v0A, v0B);
    __syncthreads();
    for (int gh = 0; gh <= ghmax; gh += 2) {
        if (gh < ghmax) stage(gh + 1, k1A, k1B, v1A, v1B);
        if (gh <= my_last) compute(gh, k0A, k0B, v0A, v0B);
        __syncthreads();
        if (gh + 1 < ghmax) stage(gh + 2, k0A, k0B, v0A, v0B);
        if (gh + 1 <= my_last) compute(gh + 1, k1A, k1B, v1A, v1B);
        __syncthreads();
    }

    // ---- normalize + store ----
#pragma unroll
    for (int i = 0; i < 2; ++i) {
        float linv[4];
#pragma unroll
        for (int r = 0; r < 4; ++r) linv[r] = 1.0f / acc_l[i][r];
#pragma unroll
        for (int jd = 0; jd < 4; ++jd)
#pragma unroll
            for (int r = 0; r < 4; ++r) {
                int rowg = q0 + w * 32 + i * 16 + q4 * 4 + r;
                Om[(size_t)rowg * HID + h * HD + jd * 16 + n16] = (bf16_t)(acc[i][jd][r] * linv[r]);
            }
    }
}

// ---------------------------------------------------------------------------
extern "C" void kernel_launch(void* const* d_in, const int* in_sizes, int n_in,
                              void* d_out, int out_size, void* d_ws, size_t ws_size,
                              hipStream_t stream)
{
    const float* X  = (const float*)d_in[0];
    const float* Wq = (const float*)d_in[1];
    const float* Wk = (const float*)d_in[2];
    const float* Wv = (const float*)d_in[3];
    const float* Wo = (const float*)d_in[4];
    float* out = (float*)d_out;

    bf16_t* Xb  = (bf16_t*)d_ws;                      // [SEQ][HID]     8 MB
    bf16_t* Wqb = Xb  + (size_t)NX;                   // [2048][2048]   8 MB
    bf16_t* Wkb = Wqb + (size_t)NWQ;                  // [512][2048]    2 MB
    bf16_t* Wvb = Wkb + (size_t)NWK;                  // [512][2048]    2 MB
    bf16_t* Wob = Wvb + (size_t)NWV;                  // [2048][2048]   8 MB
    bf16_t* Qb  = Wob + (size_t)NWO;                  // [SEQ][NH*HD]   8 MB (pre-scaled QSCALE)
    bf16_t* Kb  = Qb  + (size_t)SEQ * (NH * HD);      // [SEQ][KVDIM]   2 MB
    bf16_t* Vt  = Kb  + (size_t)SEQ * KVDIM;          // [KVDIM][SEQ]   2 MB
    bf16_t* Ob  = Vt  + (size_t)SEQ * KVDIM;          // [SEQ][NH*HD]   8 MB

    dim3 blk(256);

    cvt_all<<<dim3((NTOT / 8 + 255) / 256), blk, 0, stream>>>(X, Wq, Wk, Wv, Wo, Xb, Wqb, Wkb, Wvb, Wob);

    qkv_gemm<<<dim3(SEQ / 128, (NH * HD + 2 * KVDIM) / 64), blk, 0, stream>>>(Xb, Wqb, Wkb, Wvb, Qb, Kb, Vt);

    attn_mfma<<<dim3((SEQ / 128) * NH), blk, 0, stream>>>(Qb, Kb, Vt, Ob);

    o_gemm<<<dim3(SEQ / 128, HID / 64), blk, 0, stream>>>(Ob, Wob, out);
}